// Round 15
// baseline (411.743 us; speedup 1.0000x reference)
//
#include <hip/hip_runtime.h>
#include <hip/hip_fp16.h>

// Problem constants (fixed by the reference)
static constexpr int NN  = 50000;   // nodes (even, < 65536 so ids fit u16)
static constexpr int EE  = 800000;  // edges
static constexpr int CIN = 96;      // input channels
static constexpr int L1C = 70, S1 = 72;   // TAG layer 1 out, padded stride (9x16B)
static constexpr int L2C = 43, S2P = 48;  // TAG layer 2 out, padded stride (6x16B)

// bf16 weight image sizes (in uints = 2 bf16)
static constexpr int IMG1U = CIN * S1 / 2;    // 3456
static constexpr int IMG2U = S1 * S2P / 2;    // 1728
static constexpr int IMGHU = S2P * 32 / 2;    // 768
static constexpr int NU1 = 4 * IMG1U;         // 13824
static constexpr int NU2 = 4 * IMG2U;         // 6912
static constexpr int TUW = NU1 + NU2 + IMGHU; // 21504 uints
static constexpr int NBF = S1 + S2P;          // bias floats (72 + 48)

static constexpr int NSLICE = 8;
static constexpr int SLICEN = NN / NSLICE;    // 6250
static constexpr int NCHUNK = (NN + 63) / 64; // 782 64-node chunks

// ------------------------------------------------------------ bf16 helpers
__device__ __forceinline__ float bf_lo(unsigned int u) {
    return __uint_as_float(u << 16);
}
__device__ __forceinline__ float bf_hi(unsigned int u) {
    return __uint_as_float(u & 0xffff0000u);
}
__device__ __forceinline__ unsigned int bf_rne_bits(float f) {
    unsigned int u = __float_as_uint(f);
    return u + 0x7fffu + ((u >> 16) & 1u);
}
__device__ __forceinline__ unsigned int pack_bf(float a, float b) {
    return (bf_rne_bits(a) >> 16) | (bf_rne_bits(b) & 0xffff0000u);
}
__device__ __forceinline__ float4 unpack_bf4(uint2 q) {
    return make_float4(bf_lo(q.x), bf_hi(q.x), bf_lo(q.y), bf_hi(q.y));
}
__device__ __forceinline__ void unpack_bf8(uint4 q, float* f) {
    f[0] = bf_lo(q.x); f[1] = bf_hi(q.x); f[2] = bf_lo(q.y); f[3] = bf_hi(q.y);
    f[4] = bf_lo(q.z); f[5] = bf_hi(q.z); f[6] = bf_lo(q.w); f[7] = bf_hi(q.w);
}

// edge record: src (low 16) | fp16 weight (high 16)
__device__ __forceinline__ int rec_src(unsigned int p) { return (int)(p & 0xffffu); }
__device__ __forceinline__ float rec_w(unsigned int p) {
    return __half2float(__ushort_as_half((unsigned short)(p >> 16)));
}

// ---------------------------------------------------------------- preprocessing

__global__ void hist_kernel(const int* __restrict__ col, int* __restrict__ deg, int E) {
    int e = blockIdx.x * blockDim.x + threadIdx.x;
    if (e < E) atomicAdd(&deg[col[e]], 1);
}

static constexpr int SB = 256;  // scan block size

__global__ void reduce_kernel(const int* __restrict__ deg, int* __restrict__ bsum, int n) {
    __shared__ int sd[SB];
    int i = blockIdx.x * SB + threadIdx.x;
    sd[threadIdx.x] = (i < n) ? deg[i] : 0;
    __syncthreads();
    for (int s = SB / 2; s > 0; s >>= 1) {
        if (threadIdx.x < s) sd[threadIdx.x] += sd[threadIdx.x + s];
        __syncthreads();
    }
    if (threadIdx.x == 0) bsum[blockIdx.x] = sd[0];
}

__global__ void scan_sums_kernel(int* __restrict__ bsum, int nb) {
    __shared__ int sd[SB];
    int v = (threadIdx.x < nb) ? bsum[threadIdx.x] : 0;
    sd[threadIdx.x] = v;
    __syncthreads();
    for (int s = 1; s < SB; s <<= 1) {
        int t = (threadIdx.x >= s) ? sd[threadIdx.x - s] : 0;
        __syncthreads();
        sd[threadIdx.x] += t;
        __syncthreads();
    }
    if (threadIdx.x < nb) bsum[threadIdx.x] = sd[threadIdx.x] - v;  // exclusive
}

__global__ void block_scan_kernel(const int* __restrict__ deg, const int* __restrict__ bsum,
                                  int* __restrict__ off, int* __restrict__ cursor,
                                  float* __restrict__ dis, float* __restrict__ dis2, int n) {
    __shared__ int sd[SB];
    int i = blockIdx.x * SB + threadIdx.x;
    int v = (i < n) ? deg[i] : 0;
    sd[threadIdx.x] = v;
    __syncthreads();
    for (int s = 1; s < SB; s <<= 1) {
        int t = (threadIdx.x >= s) ? sd[threadIdx.x - s] : 0;
        __syncthreads();
        sd[threadIdx.x] += t;
        __syncthreads();
    }
    if (i < n) {
        int e = bsum[blockIdx.x] + sd[threadIdx.x] - v;
        off[i] = e;
        cursor[i] = e;
        dis[i]  = (v > 0) ? rsqrtf((float)v) : 0.0f;
        dis2[i] = rsqrtf((float)v + 1.0f);
        if (i == n - 1) off[n] = e + v;
    }
}

// Per-64-node-chunk degree sort (bitonic): equalizes degrees within each agg
// wave so the edge loop doesn't run to the wave-max degree with masked lanes
// (Poisson(16) degrees -> wave max ~26 vs mean 16 = ~60% lane efficiency).
__global__ void dsort_kernel(const int* __restrict__ deg,
                             unsigned short* __restrict__ snode, int n) {
    __shared__ unsigned int kv[64];
    int base = blockIdx.x * 64;
    int i = threadIdx.x;
    int node = base + i;
    unsigned int key = (node < n) ? (unsigned int)deg[node] : 0xffffu;
    kv[i] = (key << 16) | (unsigned int)i;
    __syncthreads();
    for (int k = 2; k <= 64; k <<= 1) {
        for (int j = k >> 1; j > 0; j >>= 1) {
            int ixj = i ^ j;
            if (ixj > i) {
                unsigned int a = kv[i], b = kv[ixj];
                bool asc = ((i & k) == 0);
                if ((a > b) == asc) { kv[i] = b; kv[ixj] = a; }
            }
            __syncthreads();
        }
    }
    snode[base + i] = (unsigned short)(base + (kv[i] & 0xffffu));
}

// Destination-sliced fill (r12-proven: blockIdx%8 -> XCD round-robin keeps each
// eTag line assembled in one L2; WRITE 55->31MB). Plain cached loads/stores
// (r13: NT loads no-op on gfx950; r10: NT stores pessimal).
__global__ void fill_kernel(const int* __restrict__ row, const int* __restrict__ col,
                            const float* __restrict__ dis, int* __restrict__ cursor,
                            unsigned int* __restrict__ eTag, int E) {
    int s = blockIdx.x & (NSLICE - 1);
    int nlo = s * SLICEN, nhi = nlo + SLICEN;
    int stride = (gridDim.x >> 3) * blockDim.x;
    for (int e = (blockIdx.x >> 3) * blockDim.x + threadIdx.x; e < E; e += stride) {
        int c = col[e];
        if (c >= nlo && c < nhi) {
            int r = row[e];
            int pos = atomicAdd(&cursor[c], 1);
            unsigned short h = __half_as_ushort(__float2half(dis[r] * dis[c]));
            eTag[pos] = (unsigned int)r | ((unsigned int)h << 16);
        }
    }
}

// repack weights into padded bf16 global images + padded fp32 biases
__global__ void wpad_kernel(const float* __restrict__ W1, const float* __restrict__ b1,
                            const float* __restrict__ W2, const float* __restrict__ b2,
                            const float* __restrict__ Wmu, const float* __restrict__ Wls,
                            unsigned int* __restrict__ wB, float* __restrict__ bB) {
    int i = blockIdx.x * blockDim.x + threadIdx.x;
    if (i < TUW) {
        float v0 = 0.f, v1 = 0.f;
        if (i < NU1) {
            int img = i / IMG1U, r = i - img * IMG1U;
            int k = r / (S1 / 2), c0 = (r - k * (S1 / 2)) * 2;
            const float* Wi = W1 + (size_t)img * CIN * L1C + (size_t)k * L1C;
            if (c0 < L1C) v0 = Wi[c0];
            if (c0 + 1 < L1C) v1 = Wi[c0 + 1];
        } else if (i < NU1 + NU2) {
            int j = i - NU1;
            int img = j / IMG2U, r = j - img * IMG2U;
            int k = r / (S2P / 2), c0 = (r - k * (S2P / 2)) * 2;
            if (k < L1C) {
                const float* Wi = W2 + (size_t)img * L1C * L2C + (size_t)k * L2C;
                if (c0 < L2C) v0 = Wi[c0];
                if (c0 + 1 < L2C) v1 = Wi[c0 + 1];
            }
        } else {
            int j = i - NU1 - NU2;
            int k = j / 16, c0 = (j - k * 16) * 2;  // 32 cols -> 16 uints per row
            if (k < L2C) {
                v0 = (c0 < 16) ? Wmu[k * 16 + c0] : Wls[k * 16 + (c0 - 16)];
                int c1 = c0 + 1;
                v1 = (c1 < 16) ? Wmu[k * 16 + c1] : Wls[k * 16 + (c1 - 16)];
            }
        }
        wB[i] = pack_bf(v0, v1);
    } else if (i < TUW + NBF) {
        int j = i - TUW;
        float v = 0.f;
        if (j < S1) { if (j < L1C) v = b1[j]; }
        else { int k = j - S1; if (k < L2C) v = b2[k]; }
        bB[j] = v;
    }
}

// ------------------------------------------------------------- aggregation (bf16)
// Chunk-sorted wide-gather: block = one 64-node chunk (blockDim = TPN*64),
// nodes processed in per-chunk degree order via snode. Writes stay inside the
// chunk's contiguous region (same block/XCD -> full-line writebacks).
template <int C, bool HASADD, bool RELU>
__global__ void aggw_kernel(const unsigned short* __restrict__ in, const unsigned short* addv,
                            unsigned short* out, const int* __restrict__ off,
                            const unsigned int* __restrict__ ep,
                            const unsigned short* __restrict__ snode, int n) {
    constexpr int TPN = C / 8;  // threads per node (8 bf16 channels each)
    int base = blockIdx.x * 64;
    int r = threadIdx.x / TPN;
    if (base + r >= n) return;               // invalid slots sort to the end
    int node = snode[base + r];
    int cc = (threadIdx.x - r * TPN) * 8;
    int beg = off[node], end = off[node + 1];
    float a0[8], a1[8];
    #pragma unroll
    for (int j = 0; j < 8; ++j) { a0[j] = 0.f; a1[j] = 0.f; }
    int e = beg;
    for (; e + 4 <= end; e += 4) {
        unsigned int p0 = ep[e], p1 = ep[e + 1], p2 = ep[e + 2], p3 = ep[e + 3];
        float w0 = rec_w(p0), w1 = rec_w(p1), w2 = rec_w(p2), w3 = rec_w(p3);
        uint4 q0 = *reinterpret_cast<const uint4*>(in + (size_t)rec_src(p0) * C + cc);
        uint4 q1 = *reinterpret_cast<const uint4*>(in + (size_t)rec_src(p1) * C + cc);
        uint4 q2 = *reinterpret_cast<const uint4*>(in + (size_t)rec_src(p2) * C + cc);
        uint4 q3 = *reinterpret_cast<const uint4*>(in + (size_t)rec_src(p3) * C + cc);
        float f[8];
        unpack_bf8(q0, f);
        #pragma unroll
        for (int j = 0; j < 8; ++j) a0[j] += w0 * f[j];
        unpack_bf8(q1, f);
        #pragma unroll
        for (int j = 0; j < 8; ++j) a1[j] += w1 * f[j];
        unpack_bf8(q2, f);
        #pragma unroll
        for (int j = 0; j < 8; ++j) a0[j] += w2 * f[j];
        unpack_bf8(q3, f);
        #pragma unroll
        for (int j = 0; j < 8; ++j) a1[j] += w3 * f[j];
    }
    for (; e < end; ++e) {
        unsigned int p = ep[e];
        float w = rec_w(p);
        uint4 q = *reinterpret_cast<const uint4*>(in + (size_t)rec_src(p) * C + cc);
        float f[8];
        unpack_bf8(q, f);
        #pragma unroll
        for (int j = 0; j < 8; ++j) a0[j] += w * f[j];
    }
    float rr[8];
    #pragma unroll
    for (int j = 0; j < 8; ++j) rr[j] = a0[j] + a1[j];
    if constexpr (HASADD) {
        uint4 qa = *reinterpret_cast<const uint4*>(addv + (size_t)node * C + cc);
        float f[8];
        unpack_bf8(qa, f);
        #pragma unroll
        for (int j = 0; j < 8; ++j) rr[j] += f[j];
    }
    if constexpr (RELU) {
        #pragma unroll
        for (int j = 0; j < 8; ++j) rr[j] = fmaxf(rr[j], 0.f);
    }
    uint4 o;
    o.x = pack_bf(rr[0], rr[1]); o.y = pack_bf(rr[2], rr[3]);
    o.z = pack_bf(rr[4], rr[5]); o.w = pack_bf(rr[6], rr[7]);
    *reinterpret_cast<uint4*>(out + (size_t)node * C + cc) = o;
}

// GCN agg + self-loop + bias + split-store, fused final stage. bf16 yh; chunk-
// sorted (TPN=4, block=256=4x64); GCN edge weight from dis2 table.
__global__ void agg_gcn_final_kernel(const unsigned short* __restrict__ yh,
                                     const int* __restrict__ off,
                                     const unsigned int* __restrict__ ep,
                                     const float* __restrict__ dis2,
                                     const float* __restrict__ bmu,
                                     const float* __restrict__ bls,
                                     const unsigned short* __restrict__ snode,
                                     float* __restrict__ outp, int n) {
    int base = blockIdx.x * 64;
    int r = threadIdx.x >> 2;
    if (base + r >= n) return;
    int node = snode[base + r];
    int cc = (threadIdx.x & 3) * 8;
    int beg = off[node], end = off[node + 1];
    float a0[8], a1[8];
    #pragma unroll
    for (int j = 0; j < 8; ++j) { a0[j] = 0.f; a1[j] = 0.f; }
    int e = beg;
    for (; e + 2 <= end; e += 2) {
        int s0 = rec_src(ep[e]), s1 = rec_src(ep[e + 1]);
        float w0 = dis2[s0], w1 = dis2[s1];
        uint4 q0 = *reinterpret_cast<const uint4*>(yh + (size_t)s0 * 32 + cc);
        uint4 q1 = *reinterpret_cast<const uint4*>(yh + (size_t)s1 * 32 + cc);
        float f[8];
        unpack_bf8(q0, f);
        #pragma unroll
        for (int j = 0; j < 8; ++j) a0[j] += w0 * f[j];
        unpack_bf8(q1, f);
        #pragma unroll
        for (int j = 0; j < 8; ++j) a1[j] += w1 * f[j];
    }
    for (; e < end; ++e) {
        int s = rec_src(ep[e]);
        float w = dis2[s];
        uint4 q = *reinterpret_cast<const uint4*>(yh + (size_t)s * 32 + cc);
        float f[8];
        unpack_bf8(q, f);
        #pragma unroll
        for (int j = 0; j < 8; ++j) a0[j] += w * f[j];
    }
    float d = dis2[node];
    uint4 qy = *reinterpret_cast<const uint4*>(yh + (size_t)node * 32 + cc);
    float yv[8];
    unpack_bf8(qy, yv);
    const float* bp = (cc < 16) ? (bmu + cc) : (bls + (cc - 16));
    float rr[8];
    #pragma unroll
    for (int j = 0; j < 8; ++j)
        rr[j] = d * (a0[j] + a1[j]) + d * d * yv[j] + bp[j];
    size_t o = (cc < 16) ? ((size_t)node * 16 + cc)
                         : ((size_t)n * 16 + (size_t)node * 16 + (cc - 16));
    *reinterpret_cast<float4*>(outp + o) = make_float4(rr[0], rr[1], rr[2], rr[3]);
    *reinterpret_cast<float4*>(outp + o + 4) = make_float4(rr[4], rr[5], rr[6], rr[7]);
}

// ----------------------------------------------------------------- matmul
__device__ __forceinline__ void fma4(float4& a, float s, const float4& w) {
    a.x += s * w.x; a.y += s * w.y; a.z += s * w.z; a.w += s * w.w;
}

// Fused multi-W matmul, bf16 weights staged in LDS.
// out_w[n0..n0+1, c0..c0+3] = X[n0..n0+1, :] @ W_w (+bias on w=0).
template <int KR, int PC, int NW, bool XBF, bool OBF, bool BIAS>
__global__ void mml_kernel(const void* __restrict__ Xv, const unsigned int* __restrict__ Wp,
                           const float* __restrict__ bp,
                           void* __restrict__ o0v, void* __restrict__ o1v,
                           void* __restrict__ o2v, void* __restrict__ o3v, int n) {
    constexpr int CP4 = PC / 4;
    constexpr int PCU = PC / 2;
    constexpr int WU = NW * KR * PCU;
    __shared__ __align__(16) unsigned int Wl[WU];
    __shared__ __align__(16) float bl[PC];
    {
        const uint4* s4 = reinterpret_cast<const uint4*>(Wp);
        uint4* d4 = reinterpret_cast<uint4*>(Wl);
        for (int i = threadIdx.x; i < WU / 4; i += blockDim.x) d4[i] = s4[i];
        if constexpr (BIAS)
            for (int i = threadIdx.x; i < PC; i += blockDim.x) bl[i] = bp[i];
    }
    __syncthreads();
    int idx = blockIdx.x * blockDim.x + threadIdx.x;
    if (idx >= (n >> 1) * CP4) return;
    int pair = idx / CP4;
    int c0 = (idx - pair * CP4) * 4;
    int n0 = pair * 2;
    const float* xaf = (const float*)Xv + (size_t)n0 * KR;
    const float* xbf = xaf + KR;
    const unsigned short* xah = (const unsigned short*)Xv + (size_t)n0 * KR;
    const unsigned short* xbh = xah + KR;
    const unsigned int* wc = Wl + (c0 >> 1);
    float4 acc[2][NW];
    #pragma unroll
    for (int w = 0; w < NW; ++w) {
        acc[0][w] = make_float4(0.f, 0.f, 0.f, 0.f);
        acc[1][w] = acc[0][w];
    }
    if constexpr (BIAS) {
        acc[0][0] = *reinterpret_cast<const float4*>(&bl[c0]);
        acc[1][0] = acc[0][0];
    }
    #pragma unroll 2
    for (int k4 = 0; k4 < KR / 4; ++k4) {
        float4 va, vb;
        if constexpr (XBF) {
            va = unpack_bf4(*reinterpret_cast<const uint2*>(xah + k4 * 4));
            vb = unpack_bf4(*reinterpret_cast<const uint2*>(xbh + k4 * 4));
        } else {
            va = *reinterpret_cast<const float4*>(xaf + k4 * 4);
            vb = *reinterpret_cast<const float4*>(xbf + k4 * 4);
        }
        #pragma unroll
        for (int j = 0; j < 4; ++j) {
            int k = k4 * 4 + j;
            float sa = (&va.x)[j];
            float sb = (&vb.x)[j];
            #pragma unroll
            for (int w = 0; w < NW; ++w) {
                uint2 q = *reinterpret_cast<const uint2*>(wc + (size_t)(w * KR + k) * PCU);
                float4 wv = unpack_bf4(q);
                fma4(acc[0][w], sa, wv);
                fma4(acc[1][w], sb, wv);
            }
        }
    }
    void* outs[4] = {o0v, o1v, o2v, o3v};
    #pragma unroll
    for (int w = 0; w < NW; ++w) {
        if constexpr (OBF) {
            unsigned short* o = (unsigned short*)outs[w] + (size_t)n0 * PC + c0;
            *reinterpret_cast<uint2*>(o) =
                make_uint2(pack_bf(acc[0][w].x, acc[0][w].y), pack_bf(acc[0][w].z, acc[0][w].w));
            *reinterpret_cast<uint2*>(o + PC) =
                make_uint2(pack_bf(acc[1][w].x, acc[1][w].y), pack_bf(acc[1][w].z, acc[1][w].w));
        } else {
            float* o = (float*)outs[w] + (size_t)n0 * PC + c0;
            *reinterpret_cast<float4*>(o) = acc[0][w];
            *reinterpret_cast<float4*>(o + PC) = acc[1][w];
        }
    }
}

// ------------------------------------------------------------------ launch

extern "C" void kernel_launch(void* const* d_in, const int* in_sizes, int n_in,
                              void* d_out, int out_size, void* d_ws, size_t ws_size,
                              hipStream_t stream) {
    const float* x   = (const float*)d_in[0];
    const int*   ei  = (const int*)d_in[1];
    const float* W1  = (const float*)d_in[2];
    const float* b1  = (const float*)d_in[3];
    const float* W2  = (const float*)d_in[4];
    const float* b2  = (const float*)d_in[5];
    const float* Wmu = (const float*)d_in[6];
    const float* bmu = (const float*)d_in[7];
    const float* Wls = (const float*)d_in[8];
    const float* bls = (const float*)d_in[9];
    float* out = (float*)d_out;

    const int N = NN, E = EE;
    const int* row = ei;
    const int* col = ei + E;

    // workspace carve-up (256B aligned)
    char* p = (char*)d_ws;
    auto alloc = [&](size_t bytes) -> char* {
        char* r = p;
        p += (bytes + 255) & ~(size_t)255;
        return r;
    };
    int*   deg    = (int*)alloc((size_t)N * 4);
    int*   off    = (int*)alloc((size_t)(N + 1) * 4);
    int*   cursor = (int*)alloc((size_t)N * 4);
    int*   bsum   = (int*)alloc((size_t)256 * 4);
    float* dis    = (float*)alloc((size_t)N * 4);
    float* dis2   = (float*)alloc((size_t)N * 4);
    unsigned int* wB = (unsigned int*)alloc((size_t)TUW * 4);
    float* bB     = (float*)alloc((size_t)NBF * 4);
    unsigned int* eTag = (unsigned int*)alloc((size_t)E * 4);
    unsigned short* snode = (unsigned short*)alloc((size_t)NCHUNK * 64 * 2);
    unsigned short* y0 = (unsigned short*)alloc((size_t)N * S1 * 2);
    unsigned short* y1 = (unsigned short*)alloc((size_t)N * S1 * 2);
    unsigned short* y2 = (unsigned short*)alloc((size_t)N * S1 * 2);
    unsigned short* y3 = (unsigned short*)alloc((size_t)N * S1 * 2);
    unsigned short* u0 = (unsigned short*)alloc((size_t)N * S2P * 2);
    unsigned short* u1 = (unsigned short*)alloc((size_t)N * S2P * 2);
    unsigned short* u2 = (unsigned short*)alloc((size_t)N * S2P * 2);
    unsigned short* u3 = (unsigned short*)alloc((size_t)N * S2P * 2);
    unsigned short* yh = (unsigned short*)alloc((size_t)N * 32 * 2);

    const unsigned int* W1b = wB;
    const unsigned int* W2b = wB + NU1;
    const unsigned int* Whb = wB + NU1 + NU2;
    const float* b1p = bB;
    const float* b2p = bB + S1;

    const int B = 256;
    int gE = (E + B - 1) / B;
    int nb = (N + SB - 1) / SB;  // 196 scan blocks

    // --- graph preprocessing -> CSR by destination (+ weight repack to bf16)
    hipMemsetAsync(deg, 0, (size_t)N * 4, stream);
    wpad_kernel<<<(TUW + NBF + B - 1) / B, B, 0, stream>>>(W1, b1, W2, b2, Wmu, Wls, wB, bB);
    hist_kernel<<<gE, B, 0, stream>>>(col, deg, E);
    reduce_kernel<<<nb, SB, 0, stream>>>(deg, bsum, N);
    scan_sums_kernel<<<1, SB, 0, stream>>>(bsum, nb);
    block_scan_kernel<<<nb, SB, 0, stream>>>(deg, bsum, off, cursor, dis, dis2, N);
    dsort_kernel<<<NCHUNK, 64, 0, stream>>>(deg, snode, N);
    fill_kernel<<<3200, B, 0, stream>>>(row, col, dis, cursor, eTag, E);

    // grids
    int gm1 = ((N / 2) * (S1 / 4) + B - 1) / B;   // 1758
    int gm2 = ((N / 2) * (S2P / 4) + B - 1) / B;  // 1172
    int gmh = ((N / 2) * 8 + B - 1) / B;          // 782

    // --- TAG layer 1 via Horner: o1 = relu(y0 + A(y1 + A(y2 + A*y3)))
    mml_kernel<CIN, S1, 2, false, true, true ><<<gm1, B, 0, stream>>>(
        x, W1b, b1p, y0, y1, nullptr, nullptr, N);
    mml_kernel<CIN, S1, 2, false, true, false><<<gm1, B, 0, stream>>>(
        x, W1b + 2 * IMG1U, nullptr, y2, y3, nullptr, nullptr, N);
    aggw_kernel<S1, true, false><<<NCHUNK, 9 * 64, 0, stream>>>(y3, y2, y2, off, eTag, snode, N);
    aggw_kernel<S1, true, false><<<NCHUNK, 9 * 64, 0, stream>>>(y2, y1, y1, off, eTag, snode, N);
    aggw_kernel<S1, true, true ><<<NCHUNK, 9 * 64, 0, stream>>>(y1, y0, y0, off, eTag, snode, N);
    // o1 = y0 (bf16, stride S1, pad cols zero)

    // --- TAG layer 2 via Horner: o2 = relu(u0 + A(u1 + A(u2 + A*u3)))
    mml_kernel<S1, S2P, 4, true, true, true ><<<gm2, B, 0, stream>>>(
        y0, W2b, b2p, u0, u1, u2, u3, N);
    aggw_kernel<S2P, true, false><<<NCHUNK, 6 * 64, 0, stream>>>(u3, u2, u2, off, eTag, snode, N);
    aggw_kernel<S2P, true, false><<<NCHUNK, 6 * 64, 0, stream>>>(u2, u1, u1, off, eTag, snode, N);
    aggw_kernel<S2P, true, true ><<<NCHUNK, 6 * 64, 0, stream>>>(u1, u0, u0, off, eTag, snode, N);
    // o2 = u0 (bf16, stride S2P, pad cols zero)

    // --- GCN heads: head matmul (bf16 in LDS, bf16 out), then fused final agg
    mml_kernel<S2P, 32, 1, true, true, false><<<gmh, B, 0, stream>>>(
        u0, Whb, nullptr, yh, nullptr, nullptr, nullptr, N);
    agg_gcn_final_kernel<<<NCHUNK, 256, 0, stream>>>(yh, off, eTag, dis2, bmu, bls, snode, out, N);
}

// Round 16
// 387.066 us; speedup vs baseline: 1.0638x; 1.0638x over previous
//
#include <hip/hip_runtime.h>
#include <hip/hip_fp16.h>

// Problem constants (fixed by the reference)
static constexpr int NN  = 50000;   // nodes (even, < 65536 so ids fit u16)
static constexpr int EE  = 800000;  // edges
static constexpr int CIN = 96;      // input channels
static constexpr int L1C = 70, S1 = 72;   // TAG layer 1 out, padded stride (9x16B)
static constexpr int L2C = 43, S2P = 48;  // TAG layer 2 out, padded stride (6x16B)

// bf16 weight image sizes (in uints = 2 bf16)
static constexpr int IMG1U = CIN * S1 / 2;    // 3456
static constexpr int IMG2U = S1 * S2P / 2;    // 1728
static constexpr int IMGHU = S2P * 32 / 2;    // 768
static constexpr int NU1 = 4 * IMG1U;         // 13824
static constexpr int NU2 = 4 * IMG2U;         // 6912
static constexpr int TUW = NU1 + NU2 + IMGHU; // 21504 uints
static constexpr int NBF = S1 + S2P;          // bias floats (72 + 48)

static constexpr int NSLICE = 8;
static constexpr int SLICEN = NN / NSLICE;    // 6250

// ------------------------------------------------------------ bf16 helpers
__device__ __forceinline__ float bf_lo(unsigned int u) {
    return __uint_as_float(u << 16);
}
__device__ __forceinline__ float bf_hi(unsigned int u) {
    return __uint_as_float(u & 0xffff0000u);
}
__device__ __forceinline__ unsigned int bf_rne_bits(float f) {
    unsigned int u = __float_as_uint(f);
    return u + 0x7fffu + ((u >> 16) & 1u);
}
__device__ __forceinline__ unsigned int pack_bf(float a, float b) {
    return (bf_rne_bits(a) >> 16) | (bf_rne_bits(b) & 0xffff0000u);
}
__device__ __forceinline__ float4 unpack_bf4(uint2 q) {
    return make_float4(bf_lo(q.x), bf_hi(q.x), bf_lo(q.y), bf_hi(q.y));
}
__device__ __forceinline__ void unpack_bf8(uint4 q, float* f) {
    f[0] = bf_lo(q.x); f[1] = bf_hi(q.x); f[2] = bf_lo(q.y); f[3] = bf_hi(q.y);
    f[4] = bf_lo(q.z); f[5] = bf_hi(q.z); f[6] = bf_lo(q.w); f[7] = bf_hi(q.w);
}

// edge record: src (low 16) | fp16 weight (high 16)
__device__ __forceinline__ int rec_src(unsigned int p) { return (int)(p & 0xffffu); }
__device__ __forceinline__ float rec_w(unsigned int p) {
    return __half2float(__ushort_as_half((unsigned short)(p >> 16)));
}

// ---------------------------------------------------------------- preprocessing

// Fused init: zero deg + repack weights into padded bf16 images + fp32 biases.
// (One launch instead of memset + wpad.)
__global__ void init_kernel(const float* __restrict__ W1, const float* __restrict__ b1,
                            const float* __restrict__ W2, const float* __restrict__ b2,
                            const float* __restrict__ Wmu, const float* __restrict__ Wls,
                            unsigned int* __restrict__ wB, float* __restrict__ bB,
                            int* __restrict__ deg) {
    int i = blockIdx.x * blockDim.x + threadIdx.x;
    if (i < NN) deg[i] = 0;
    if (i < TUW) {
        float v0 = 0.f, v1 = 0.f;
        if (i < NU1) {
            int img = i / IMG1U, r = i - img * IMG1U;
            int k = r / (S1 / 2), c0 = (r - k * (S1 / 2)) * 2;
            const float* Wi = W1 + (size_t)img * CIN * L1C + (size_t)k * L1C;
            if (c0 < L1C) v0 = Wi[c0];
            if (c0 + 1 < L1C) v1 = Wi[c0 + 1];
        } else if (i < NU1 + NU2) {
            int j = i - NU1;
            int img = j / IMG2U, r = j - img * IMG2U;
            int k = r / (S2P / 2), c0 = (r - k * (S2P / 2)) * 2;
            if (k < L1C) {
                const float* Wi = W2 + (size_t)img * L1C * L2C + (size_t)k * L2C;
                if (c0 < L2C) v0 = Wi[c0];
                if (c0 + 1 < L2C) v1 = Wi[c0 + 1];
            }
        } else {
            int j = i - NU1 - NU2;
            int k = j / 16, c0 = (j - k * 16) * 2;  // 32 cols -> 16 uints per row
            if (k < L2C) {
                v0 = (c0 < 16) ? Wmu[k * 16 + c0] : Wls[k * 16 + (c0 - 16)];
                int c1 = c0 + 1;
                v1 = (c1 < 16) ? Wmu[k * 16 + c1] : Wls[k * 16 + (c1 - 16)];
            }
        }
        wB[i] = pack_bf(v0, v1);
    } else if (i < TUW + NBF) {
        int j = i - TUW;
        float v = 0.f;
        if (j < S1) { if (j < L1C) v = b1[j]; }
        else { int k = j - S1; if (k < L2C) v = b2[k]; }
        bB[j] = v;
    }
}

__global__ void hist_kernel(const int* __restrict__ col, int* __restrict__ deg, int E) {
    int e = blockIdx.x * blockDim.x + threadIdx.x;
    if (e < E) atomicAdd(&deg[col[e]], 1);
}

static constexpr int SB = 256;  // scan block size

__global__ void reduce_kernel(const int* __restrict__ deg, int* __restrict__ bsum, int n) {
    __shared__ int sd[SB];
    int i = blockIdx.x * SB + threadIdx.x;
    sd[threadIdx.x] = (i < n) ? deg[i] : 0;
    __syncthreads();
    for (int s = SB / 2; s > 0; s >>= 1) {
        if (threadIdx.x < s) sd[threadIdx.x] += sd[threadIdx.x + s];
        __syncthreads();
    }
    if (threadIdx.x == 0) bsum[blockIdx.x] = sd[0];
}

// Fused block scan: each block computes its own bsum prefix (196-element
// block-reduce — cheaper than a separate scan_sums launch + drain), then the
// local exclusive scan; emits off/cursor/dis/dis2.
__global__ void block_scan_kernel(const int* __restrict__ deg, const int* __restrict__ bsum,
                                  int* __restrict__ off, int* __restrict__ cursor,
                                  float* __restrict__ dis, float* __restrict__ dis2,
                                  int n, int nb) {
    __shared__ int sd[SB];
    __shared__ int bofs;
    int t = threadIdx.x;
    // prefix of bsum[0..blockIdx.x)
    sd[t] = (t < nb && t < (int)blockIdx.x) ? bsum[t] : 0;
    __syncthreads();
    for (int s = SB / 2; s > 0; s >>= 1) {
        if (t < s) sd[t] += sd[t + s];
        __syncthreads();
    }
    if (t == 0) bofs = sd[0];
    __syncthreads();
    int i = blockIdx.x * SB + t;
    int v = (i < n) ? deg[i] : 0;
    sd[t] = v;
    __syncthreads();
    for (int s = 1; s < SB; s <<= 1) {
        int tv = (t >= s) ? sd[t - s] : 0;
        __syncthreads();
        sd[t] += tv;
        __syncthreads();
    }
    if (i < n) {
        int e = bofs + sd[t] - v;
        off[i] = e;
        cursor[i] = e;
        dis[i]  = (v > 0) ? rsqrtf((float)v) : 0.0f;
        dis2[i] = rsqrtf((float)v + 1.0f);
        if (i == n - 1) off[n] = e + v;
    }
}

// Destination-sliced fill (r12-proven: blockIdx%8 -> XCD round-robin keeps each
// eTag line assembled in one L2; WRITE 55->31MB). Plain cached loads/stores
// (r13: NT loads no-op on gfx950; r10: NT stores pessimal).
__global__ void fill_kernel(const int* __restrict__ row, const int* __restrict__ col,
                            const float* __restrict__ dis, int* __restrict__ cursor,
                            unsigned int* __restrict__ eTag, int E) {
    int s = blockIdx.x & (NSLICE - 1);
    int nlo = s * SLICEN, nhi = nlo + SLICEN;
    int stride = (gridDim.x >> 3) * blockDim.x;
    for (int e = (blockIdx.x >> 3) * blockDim.x + threadIdx.x; e < E; e += stride) {
        int c = col[e];
        if (c >= nlo && c < nhi) {
            int r = row[e];
            int pos = atomicAdd(&cursor[c], 1);
            unsigned short h = __half_as_ushort(__float2half(dis[r] * dis[c]));
            eTag[pos] = (unsigned int)r | ((unsigned int)h << 16);
        }
    }
}

// ------------------------------------------------------------- aggregation (bf16)
// Wide-gather: thread = (node, 8-channel group) -> one uint4 (16B) per edge.
// out[i][:] = (HASADD ? addv[i][:] : 0) + sum_e w_e * in[src_e][:]  (+ ReLU)
template <int C, bool HASADD, bool RELU>
__global__ void aggw_kernel(const unsigned short* __restrict__ in, const unsigned short* addv,
                            unsigned short* out, const int* __restrict__ off,
                            const unsigned int* __restrict__ ep, int n) {
    constexpr int TPN = C / 8;  // threads per node (8 bf16 channels each)
    int t = blockIdx.x * blockDim.x + threadIdx.x;
    if (t >= n * TPN) return;
    int node = t / TPN;
    int cc = (t - node * TPN) * 8;
    int beg = off[node], end = off[node + 1];
    float a0[8], a1[8];
    #pragma unroll
    for (int j = 0; j < 8; ++j) { a0[j] = 0.f; a1[j] = 0.f; }
    int e = beg;
    for (; e + 4 <= end; e += 4) {
        unsigned int p0 = ep[e], p1 = ep[e + 1], p2 = ep[e + 2], p3 = ep[e + 3];
        float w0 = rec_w(p0), w1 = rec_w(p1), w2 = rec_w(p2), w3 = rec_w(p3);
        uint4 q0 = *reinterpret_cast<const uint4*>(in + (size_t)rec_src(p0) * C + cc);
        uint4 q1 = *reinterpret_cast<const uint4*>(in + (size_t)rec_src(p1) * C + cc);
        uint4 q2 = *reinterpret_cast<const uint4*>(in + (size_t)rec_src(p2) * C + cc);
        uint4 q3 = *reinterpret_cast<const uint4*>(in + (size_t)rec_src(p3) * C + cc);
        float f[8];
        unpack_bf8(q0, f);
        #pragma unroll
        for (int j = 0; j < 8; ++j) a0[j] += w0 * f[j];
        unpack_bf8(q1, f);
        #pragma unroll
        for (int j = 0; j < 8; ++j) a1[j] += w1 * f[j];
        unpack_bf8(q2, f);
        #pragma unroll
        for (int j = 0; j < 8; ++j) a0[j] += w2 * f[j];
        unpack_bf8(q3, f);
        #pragma unroll
        for (int j = 0; j < 8; ++j) a1[j] += w3 * f[j];
    }
    for (; e < end; ++e) {
        unsigned int p = ep[e];
        float w = rec_w(p);
        uint4 q = *reinterpret_cast<const uint4*>(in + (size_t)rec_src(p) * C + cc);
        float f[8];
        unpack_bf8(q, f);
        #pragma unroll
        for (int j = 0; j < 8; ++j) a0[j] += w * f[j];
    }
    float r[8];
    #pragma unroll
    for (int j = 0; j < 8; ++j) r[j] = a0[j] + a1[j];
    if constexpr (HASADD) {
        uint4 qa = *reinterpret_cast<const uint4*>(addv + (size_t)node * C + cc);
        float f[8];
        unpack_bf8(qa, f);
        #pragma unroll
        for (int j = 0; j < 8; ++j) r[j] += f[j];
    }
    if constexpr (RELU) {
        #pragma unroll
        for (int j = 0; j < 8; ++j) r[j] = fmaxf(r[j], 0.f);
    }
    uint4 o;
    o.x = pack_bf(r[0], r[1]); o.y = pack_bf(r[2], r[3]);
    o.z = pack_bf(r[4], r[5]); o.w = pack_bf(r[6], r[7]);
    *reinterpret_cast<uint4*>(out + (size_t)node * C + cc) = o;
}

// GCN agg + self-loop + bias + split-store, fused final stage. bf16 yh, 16B
// gathers (4 threads/node x 8 channels); GCN edge weight from dis2 table.
__global__ void agg_gcn_final_kernel(const unsigned short* __restrict__ yh,
                                     const int* __restrict__ off,
                                     const unsigned int* __restrict__ ep,
                                     const float* __restrict__ dis2,
                                     const float* __restrict__ bmu,
                                     const float* __restrict__ bls,
                                     float* __restrict__ outp, int n) {
    int t = blockIdx.x * blockDim.x + threadIdx.x;
    if (t >= n * 4) return;
    int node = t >> 2;
    int cc = (t & 3) * 8;
    int beg = off[node], end = off[node + 1];
    float a0[8], a1[8];
    #pragma unroll
    for (int j = 0; j < 8; ++j) { a0[j] = 0.f; a1[j] = 0.f; }
    int e = beg;
    for (; e + 2 <= end; e += 2) {
        int s0 = rec_src(ep[e]), s1 = rec_src(ep[e + 1]);
        float w0 = dis2[s0], w1 = dis2[s1];
        uint4 q0 = *reinterpret_cast<const uint4*>(yh + (size_t)s0 * 32 + cc);
        uint4 q1 = *reinterpret_cast<const uint4*>(yh + (size_t)s1 * 32 + cc);
        float f[8];
        unpack_bf8(q0, f);
        #pragma unroll
        for (int j = 0; j < 8; ++j) a0[j] += w0 * f[j];
        unpack_bf8(q1, f);
        #pragma unroll
        for (int j = 0; j < 8; ++j) a1[j] += w1 * f[j];
    }
    for (; e < end; ++e) {
        int s = rec_src(ep[e]);
        float w = dis2[s];
        uint4 q = *reinterpret_cast<const uint4*>(yh + (size_t)s * 32 + cc);
        float f[8];
        unpack_bf8(q, f);
        #pragma unroll
        for (int j = 0; j < 8; ++j) a0[j] += w * f[j];
    }
    float d = dis2[node];
    uint4 qy = *reinterpret_cast<const uint4*>(yh + (size_t)node * 32 + cc);
    float yv[8];
    unpack_bf8(qy, yv);
    const float* bp = (cc < 16) ? (bmu + cc) : (bls + (cc - 16));
    float r[8];
    #pragma unroll
    for (int j = 0; j < 8; ++j)
        r[j] = d * (a0[j] + a1[j]) + d * d * yv[j] + bp[j];
    size_t o = (cc < 16) ? ((size_t)node * 16 + cc)
                         : ((size_t)n * 16 + (size_t)node * 16 + (cc - 16));
    *reinterpret_cast<float4*>(outp + o) = make_float4(r[0], r[1], r[2], r[3]);
    *reinterpret_cast<float4*>(outp + o + 4) = make_float4(r[4], r[5], r[6], r[7]);
}

// ----------------------------------------------------------------- matmul
__device__ __forceinline__ void fma4(float4& a, float s, const float4& w) {
    a.x += s * w.x; a.y += s * w.y; a.z += s * w.z; a.w += s * w.w;
}

// Fused multi-W matmul, bf16 weights staged in LDS.
// out_w[n0..n0+1, c0..c0+3] = X[n0..n0+1, :] @ W_w (+bias on w=0).
template <int KR, int PC, int NW, bool XBF, bool OBF, bool BIAS>
__global__ void mml_kernel(const void* __restrict__ Xv, const unsigned int* __restrict__ Wp,
                           const float* __restrict__ bp,
                           void* __restrict__ o0v, void* __restrict__ o1v,
                           void* __restrict__ o2v, void* __restrict__ o3v, int n) {
    constexpr int CP4 = PC / 4;
    constexpr int PCU = PC / 2;
    constexpr int WU = NW * KR * PCU;
    __shared__ __align__(16) unsigned int Wl[WU];
    __shared__ __align__(16) float bl[PC];
    {
        const uint4* s4 = reinterpret_cast<const uint4*>(Wp);
        uint4* d4 = reinterpret_cast<uint4*>(Wl);
        for (int i = threadIdx.x; i < WU / 4; i += blockDim.x) d4[i] = s4[i];
        if constexpr (BIAS)
            for (int i = threadIdx.x; i < PC; i += blockDim.x) bl[i] = bp[i];
    }
    __syncthreads();
    int idx = blockIdx.x * blockDim.x + threadIdx.x;
    if (idx >= (n >> 1) * CP4) return;
    int pair = idx / CP4;
    int c0 = (idx - pair * CP4) * 4;
    int n0 = pair * 2;
    const float* xaf = (const float*)Xv + (size_t)n0 * KR;
    const float* xbf = xaf + KR;
    const unsigned short* xah = (const unsigned short*)Xv + (size_t)n0 * KR;
    const unsigned short* xbh = xah + KR;
    const unsigned int* wc = Wl + (c0 >> 1);
    float4 acc[2][NW];
    #pragma unroll
    for (int w = 0; w < NW; ++w) {
        acc[0][w] = make_float4(0.f, 0.f, 0.f, 0.f);
        acc[1][w] = acc[0][w];
    }
    if constexpr (BIAS) {
        acc[0][0] = *reinterpret_cast<const float4*>(&bl[c0]);
        acc[1][0] = acc[0][0];
    }
    #pragma unroll 2
    for (int k4 = 0; k4 < KR / 4; ++k4) {
        float4 va, vb;
        if constexpr (XBF) {
            va = unpack_bf4(*reinterpret_cast<const uint2*>(xah + k4 * 4));
            vb = unpack_bf4(*reinterpret_cast<const uint2*>(xbh + k4 * 4));
        } else {
            va = *reinterpret_cast<const float4*>(xaf + k4 * 4);
            vb = *reinterpret_cast<const float4*>(xbf + k4 * 4);
        }
        #pragma unroll
        for (int j = 0; j < 4; ++j) {
            int k = k4 * 4 + j;
            float sa = (&va.x)[j];
            float sb = (&vb.x)[j];
            #pragma unroll
            for (int w = 0; w < NW; ++w) {
                uint2 q = *reinterpret_cast<const uint2*>(wc + (size_t)(w * KR + k) * PCU);
                float4 wv = unpack_bf4(q);
                fma4(acc[0][w], sa, wv);
                fma4(acc[1][w], sb, wv);
            }
        }
    }
    void* outs[4] = {o0v, o1v, o2v, o3v};
    #pragma unroll
    for (int w = 0; w < NW; ++w) {
        if constexpr (OBF) {
            unsigned short* o = (unsigned short*)outs[w] + (size_t)n0 * PC + c0;
            *reinterpret_cast<uint2*>(o) =
                make_uint2(pack_bf(acc[0][w].x, acc[0][w].y), pack_bf(acc[0][w].z, acc[0][w].w));
            *reinterpret_cast<uint2*>(o + PC) =
                make_uint2(pack_bf(acc[1][w].x, acc[1][w].y), pack_bf(acc[1][w].z, acc[1][w].w));
        } else {
            float* o = (float*)outs[w] + (size_t)n0 * PC + c0;
            *reinterpret_cast<float4*>(o) = acc[0][w];
            *reinterpret_cast<float4*>(o + PC) = acc[1][w];
        }
    }
}

// ------------------------------------------------------------------ launch

extern "C" void kernel_launch(void* const* d_in, const int* in_sizes, int n_in,
                              void* d_out, int out_size, void* d_ws, size_t ws_size,
                              hipStream_t stream) {
    const float* x   = (const float*)d_in[0];
    const int*   ei  = (const int*)d_in[1];
    const float* W1  = (const float*)d_in[2];
    const float* b1  = (const float*)d_in[3];
    const float* W2  = (const float*)d_in[4];
    const float* b2  = (const float*)d_in[5];
    const float* Wmu = (const float*)d_in[6];
    const float* bmu = (const float*)d_in[7];
    const float* Wls = (const float*)d_in[8];
    const float* bls = (const float*)d_in[9];
    float* out = (float*)d_out;

    const int N = NN, E = EE;
    const int* row = ei;
    const int* col = ei + E;

    // workspace carve-up (256B aligned)
    char* p = (char*)d_ws;
    auto alloc = [&](size_t bytes) -> char* {
        char* r = p;
        p += (bytes + 255) & ~(size_t)255;
        return r;
    };
    int*   deg    = (int*)alloc((size_t)N * 4);
    int*   off    = (int*)alloc((size_t)(N + 1) * 4);
    int*   cursor = (int*)alloc((size_t)N * 4);
    int*   bsum   = (int*)alloc((size_t)256 * 4);
    float* dis    = (float*)alloc((size_t)N * 4);
    float* dis2   = (float*)alloc((size_t)N * 4);
    unsigned int* wB = (unsigned int*)alloc((size_t)TUW * 4);
    float* bB     = (float*)alloc((size_t)NBF * 4);
    unsigned int* eTag = (unsigned int*)alloc((size_t)E * 4);
    unsigned short* y0 = (unsigned short*)alloc((size_t)N * S1 * 2);
    unsigned short* y1 = (unsigned short*)alloc((size_t)N * S1 * 2);
    unsigned short* y2 = (unsigned short*)alloc((size_t)N * S1 * 2);
    unsigned short* y3 = (unsigned short*)alloc((size_t)N * S1 * 2);
    unsigned short* u0 = (unsigned short*)alloc((size_t)N * S2P * 2);
    unsigned short* u1 = (unsigned short*)alloc((size_t)N * S2P * 2);
    unsigned short* u2 = (unsigned short*)alloc((size_t)N * S2P * 2);
    unsigned short* u3 = (unsigned short*)alloc((size_t)N * S2P * 2);
    unsigned short* yh = (unsigned short*)alloc((size_t)N * 32 * 2);

    const unsigned int* W1b = wB;
    const unsigned int* W2b = wB + NU1;
    const unsigned int* Whb = wB + NU1 + NU2;
    const float* b1p = bB;
    const float* b2p = bB + S1;

    const int B = 256;
    int gE = (E + B - 1) / B;
    int nb = (N + SB - 1) / SB;  // 196 scan blocks

    // --- graph preprocessing -> CSR by destination (+ weight repack to bf16)
    init_kernel<<<nb, B, 0, stream>>>(W1, b1, W2, b2, Wmu, Wls, wB, bB, deg);
    hist_kernel<<<gE, B, 0, stream>>>(col, deg, E);
    reduce_kernel<<<nb, SB, 0, stream>>>(deg, bsum, N);
    block_scan_kernel<<<nb, SB, 0, stream>>>(deg, bsum, off, cursor, dis, dis2, N, nb);
    fill_kernel<<<3200, B, 0, stream>>>(row, col, dis, cursor, eTag, E);

    // grids
    int gm1 = ((N / 2) * (S1 / 4) + B - 1) / B;   // 1758
    int gm2 = ((N / 2) * (S2P / 4) + B - 1) / B;  // 1172
    int gmh = ((N / 2) * 8 + B - 1) / B;          // 782
    int ga72 = (N * (S1 / 8) + B - 1) / B;        // TPN 9
    int ga48 = (N * (S2P / 8) + B - 1) / B;       // TPN 6
    int gaF  = (N * 4 + B - 1) / B;               // TPN 4

    // --- TAG layer 1 via Horner: o1 = relu(y0 + A(y1 + A(y2 + A*y3)))
    mml_kernel<CIN, S1, 2, false, true, true ><<<gm1, B, 0, stream>>>(
        x, W1b, b1p, y0, y1, nullptr, nullptr, N);
    mml_kernel<CIN, S1, 2, false, true, false><<<gm1, B, 0, stream>>>(
        x, W1b + 2 * IMG1U, nullptr, y2, y3, nullptr, nullptr, N);
    aggw_kernel<S1, true, false><<<ga72, B, 0, stream>>>(y3, y2, y2, off, eTag, N);
    aggw_kernel<S1, true, false><<<ga72, B, 0, stream>>>(y2, y1, y1, off, eTag, N);
    aggw_kernel<S1, true, true ><<<ga72, B, 0, stream>>>(y1, y0, y0, off, eTag, N);
    // o1 = y0 (bf16, stride S1, pad cols zero)

    // --- TAG layer 2 via Horner: o2 = relu(u0 + A(u1 + A(u2 + A*u3)))
    mml_kernel<S1, S2P, 4, true, true, true ><<<gm2, B, 0, stream>>>(
        y0, W2b, b2p, u0, u1, u2, u3, N);
    aggw_kernel<S2P, true, false><<<ga48, B, 0, stream>>>(u3, u2, u2, off, eTag, N);
    aggw_kernel<S2P, true, false><<<ga48, B, 0, stream>>>(u2, u1, u1, off, eTag, N);
    aggw_kernel<S2P, true, true ><<<ga48, B, 0, stream>>>(u1, u0, u0, off, eTag, N);
    // o2 = u0 (bf16, stride S2P, pad cols zero)

    // --- GCN heads: head matmul (bf16 in LDS, bf16 out), then fused final agg
    mml_kernel<S2P, 32, 1, true, true, false><<<gmh, B, 0, stream>>>(
        u0, Whb, nullptr, yh, nullptr, nullptr, nullptr, N);
    agg_gcn_final_kernel<<<gaF, B, 0, stream>>>(yh, off, eTag, dis2, bmu, bls, out, N);
}

// Round 17
// 364.886 us; speedup vs baseline: 1.1284x; 1.0608x over previous
//
#include <hip/hip_runtime.h>
#include <hip/hip_fp16.h>

// Problem constants (fixed by the reference)
static constexpr int NN  = 50000;   // nodes (even, < 65536 so ids fit u16)
static constexpr int EE  = 800000;  // edges
static constexpr int CIN = 96;      // input channels
static constexpr int L1C = 70, S1 = 72;   // TAG layer 1 out, padded stride (9x16B)
static constexpr int L2C = 43, S2P = 48;  // TAG layer 2 out, padded stride (6x16B)

// bf16 weight image sizes (in uints = 2 bf16)
static constexpr int IMG1U = CIN * S1 / 2;    // 3456
static constexpr int IMG2U = S1 * S2P / 2;    // 1728
static constexpr int IMGHU = S2P * 32 / 2;    // 768
static constexpr int NU1 = 4 * IMG1U;         // 13824
static constexpr int NU2 = 4 * IMG2U;         // 6912
static constexpr int TUW = NU1 + NU2 + IMGHU; // 21504 uints
static constexpr int NBF = S1 + S2P;          // bias floats (72 + 48)

static constexpr int NSLICE = 8;
static constexpr int SLICEN = NN / NSLICE;    // 6250

// ------------------------------------------------------------ bf16 helpers
__device__ __forceinline__ float bf_lo(unsigned int u) {
    return __uint_as_float(u << 16);
}
__device__ __forceinline__ float bf_hi(unsigned int u) {
    return __uint_as_float(u & 0xffff0000u);
}
__device__ __forceinline__ unsigned int bf_rne_bits(float f) {
    unsigned int u = __float_as_uint(f);
    return u + 0x7fffu + ((u >> 16) & 1u);
}
__device__ __forceinline__ unsigned int pack_bf(float a, float b) {
    return (bf_rne_bits(a) >> 16) | (bf_rne_bits(b) & 0xffff0000u);
}
__device__ __forceinline__ float4 unpack_bf4(uint2 q) {
    return make_float4(bf_lo(q.x), bf_hi(q.x), bf_lo(q.y), bf_hi(q.y));
}
__device__ __forceinline__ void unpack_bf8(uint4 q, float* f) {
    f[0] = bf_lo(q.x); f[1] = bf_hi(q.x); f[2] = bf_lo(q.y); f[3] = bf_hi(q.y);
    f[4] = bf_lo(q.z); f[5] = bf_hi(q.z); f[6] = bf_lo(q.w); f[7] = bf_hi(q.w);
}

// edge record: src (low 16) | fp16 weight (high 16)
__device__ __forceinline__ int rec_src(unsigned int p) { return (int)(p & 0xffffu); }
__device__ __forceinline__ float rec_w(unsigned int p) {
    return __half2float(__ushort_as_half((unsigned short)(p >> 16)));
}

// ---------------------------------------------------------------- preprocessing

// Fused init: zero deg + repack weights into padded bf16 images + fp32 biases.
__global__ void init_kernel(const float* __restrict__ W1, const float* __restrict__ b1,
                            const float* __restrict__ W2, const float* __restrict__ b2,
                            const float* __restrict__ Wmu, const float* __restrict__ Wls,
                            unsigned int* __restrict__ wB, float* __restrict__ bB,
                            int* __restrict__ deg) {
    int i = blockIdx.x * blockDim.x + threadIdx.x;
    if (i < NN) deg[i] = 0;
    if (i < TUW) {
        float v0 = 0.f, v1 = 0.f;
        if (i < NU1) {
            int img = i / IMG1U, r = i - img * IMG1U;
            int k = r / (S1 / 2), c0 = (r - k * (S1 / 2)) * 2;
            const float* Wi = W1 + (size_t)img * CIN * L1C + (size_t)k * L1C;
            if (c0 < L1C) v0 = Wi[c0];
            if (c0 + 1 < L1C) v1 = Wi[c0 + 1];
        } else if (i < NU1 + NU2) {
            int j = i - NU1;
            int img = j / IMG2U, r = j - img * IMG2U;
            int k = r / (S2P / 2), c0 = (r - k * (S2P / 2)) * 2;
            if (k < L1C) {
                const float* Wi = W2 + (size_t)img * L1C * L2C + (size_t)k * L2C;
                if (c0 < L2C) v0 = Wi[c0];
                if (c0 + 1 < L2C) v1 = Wi[c0 + 1];
            }
        } else {
            int j = i - NU1 - NU2;
            int k = j / 16, c0 = (j - k * 16) * 2;  // 32 cols -> 16 uints per row
            if (k < L2C) {
                v0 = (c0 < 16) ? Wmu[k * 16 + c0] : Wls[k * 16 + (c0 - 16)];
                int c1 = c0 + 1;
                v1 = (c1 < 16) ? Wmu[k * 16 + c1] : Wls[k * 16 + (c1 - 16)];
            }
        }
        wB[i] = pack_bf(v0, v1);
    } else if (i < TUW + NBF) {
        int j = i - TUW;
        float v = 0.f;
        if (j < S1) { if (j < L1C) v = b1[j]; }
        else { int k = j - S1; if (k < L2C) v = b2[k]; }
        bB[j] = v;
    }
}

// Histogram + rank capture: the atomicAdd's return IS each edge's rank within
// its destination bucket — store it packed with row so fill needs no atomics
// (r16: fill was latency-bound on the cursor atomic's ~300cyc round-trip).
// rank < max-deg (~50) and row < 65536 both fit u16.
__global__ void hist_kernel(const int* __restrict__ row, const int* __restrict__ col,
                            int* __restrict__ deg, unsigned int* __restrict__ rr, int E) {
    int e = blockIdx.x * blockDim.x + threadIdx.x;
    if (e < E) {
        int c = col[e];
        int rk = atomicAdd(&deg[c], 1);
        rr[e] = ((unsigned int)rk << 16) | (unsigned int)row[e];
    }
}

static constexpr int SB = 256;  // scan block size

__global__ void reduce_kernel(const int* __restrict__ deg, int* __restrict__ bsum, int n) {
    __shared__ int sd[SB];
    int i = blockIdx.x * SB + threadIdx.x;
    sd[threadIdx.x] = (i < n) ? deg[i] : 0;
    __syncthreads();
    for (int s = SB / 2; s > 0; s >>= 1) {
        if (threadIdx.x < s) sd[threadIdx.x] += sd[threadIdx.x + s];
        __syncthreads();
    }
    if (threadIdx.x == 0) bsum[blockIdx.x] = sd[0];
}

// Fused block scan: each block computes its own bsum prefix, then the local
// exclusive scan; emits off/dis/dis2 (no cursor needed — fill is atomic-free).
__global__ void block_scan_kernel(const int* __restrict__ deg, const int* __restrict__ bsum,
                                  int* __restrict__ off,
                                  float* __restrict__ dis, float* __restrict__ dis2,
                                  int n, int nb) {
    __shared__ int sd[SB];
    __shared__ int bofs;
    int t = threadIdx.x;
    sd[t] = (t < nb && t < (int)blockIdx.x) ? bsum[t] : 0;
    __syncthreads();
    for (int s = SB / 2; s > 0; s >>= 1) {
        if (t < s) sd[t] += sd[t + s];
        __syncthreads();
    }
    if (t == 0) bofs = sd[0];
    __syncthreads();
    int i = blockIdx.x * SB + t;
    int v = (i < n) ? deg[i] : 0;
    sd[t] = v;
    __syncthreads();
    for (int s = 1; s < SB; s <<= 1) {
        int tv = (t >= s) ? sd[t - s] : 0;
        __syncthreads();
        sd[t] += tv;
        __syncthreads();
    }
    if (i < n) {
        int e = bofs + sd[t] - v;
        off[i] = e;
        dis[i]  = (v > 0) ? rsqrtf((float)v) : 0.0f;
        dis2[i] = rsqrtf((float)v + 1.0f);
        if (i == n - 1) off[n] = e + v;
    }
}

// Atomic-free destination-sliced fill: pos = off[c] + rank (rank captured in
// hist). Slicing kept for eTag write locality (r12: one XCD assembles each
// line). Per-edge work is now pure load->compute->store, no atomic round-trip.
__global__ void fill_kernel(const int* __restrict__ col, const unsigned int* __restrict__ rr,
                            const float* __restrict__ dis, const int* __restrict__ off,
                            unsigned int* __restrict__ eTag, int E) {
    int s = blockIdx.x & (NSLICE - 1);
    int nlo = s * SLICEN, nhi = nlo + SLICEN;
    int stride = (gridDim.x >> 3) * blockDim.x;
    for (int e = (blockIdx.x >> 3) * blockDim.x + threadIdx.x; e < E; e += stride) {
        int c = col[e];
        if (c >= nlo && c < nhi) {
            unsigned int u = rr[e];
            int r = (int)(u & 0xffffu);
            int pos = off[c] + (int)(u >> 16);
            unsigned short h = __half_as_ushort(__float2half(dis[r] * dis[c]));
            eTag[pos] = (unsigned int)r | ((unsigned int)h << 16);
        }
    }
}

// ------------------------------------------------------------- aggregation (bf16)
// Wide-gather: thread = (node, 8-channel group) -> one uint4 (16B) per edge.
// out[i][:] = (HASADD ? addv[i][:] : 0) + sum_e w_e * in[src_e][:]  (+ ReLU)
template <int C, bool HASADD, bool RELU>
__global__ void aggw_kernel(const unsigned short* __restrict__ in, const unsigned short* addv,
                            unsigned short* out, const int* __restrict__ off,
                            const unsigned int* __restrict__ ep, int n) {
    constexpr int TPN = C / 8;  // threads per node (8 bf16 channels each)
    int t = blockIdx.x * blockDim.x + threadIdx.x;
    if (t >= n * TPN) return;
    int node = t / TPN;
    int cc = (t - node * TPN) * 8;
    int beg = off[node], end = off[node + 1];
    float a0[8], a1[8];
    #pragma unroll
    for (int j = 0; j < 8; ++j) { a0[j] = 0.f; a1[j] = 0.f; }
    int e = beg;
    for (; e + 4 <= end; e += 4) {
        unsigned int p0 = ep[e], p1 = ep[e + 1], p2 = ep[e + 2], p3 = ep[e + 3];
        float w0 = rec_w(p0), w1 = rec_w(p1), w2 = rec_w(p2), w3 = rec_w(p3);
        uint4 q0 = *reinterpret_cast<const uint4*>(in + (size_t)rec_src(p0) * C + cc);
        uint4 q1 = *reinterpret_cast<const uint4*>(in + (size_t)rec_src(p1) * C + cc);
        uint4 q2 = *reinterpret_cast<const uint4*>(in + (size_t)rec_src(p2) * C + cc);
        uint4 q3 = *reinterpret_cast<const uint4*>(in + (size_t)rec_src(p3) * C + cc);
        float f[8];
        unpack_bf8(q0, f);
        #pragma unroll
        for (int j = 0; j < 8; ++j) a0[j] += w0 * f[j];
        unpack_bf8(q1, f);
        #pragma unroll
        for (int j = 0; j < 8; ++j) a1[j] += w1 * f[j];
        unpack_bf8(q2, f);
        #pragma unroll
        for (int j = 0; j < 8; ++j) a0[j] += w2 * f[j];
        unpack_bf8(q3, f);
        #pragma unroll
        for (int j = 0; j < 8; ++j) a1[j] += w3 * f[j];
    }
    for (; e < end; ++e) {
        unsigned int p = ep[e];
        float w = rec_w(p);
        uint4 q = *reinterpret_cast<const uint4*>(in + (size_t)rec_src(p) * C + cc);
        float f[8];
        unpack_bf8(q, f);
        #pragma unroll
        for (int j = 0; j < 8; ++j) a0[j] += w * f[j];
    }
    float r[8];
    #pragma unroll
    for (int j = 0; j < 8; ++j) r[j] = a0[j] + a1[j];
    if constexpr (HASADD) {
        uint4 qa = *reinterpret_cast<const uint4*>(addv + (size_t)node * C + cc);
        float f[8];
        unpack_bf8(qa, f);
        #pragma unroll
        for (int j = 0; j < 8; ++j) r[j] += f[j];
    }
    if constexpr (RELU) {
        #pragma unroll
        for (int j = 0; j < 8; ++j) r[j] = fmaxf(r[j], 0.f);
    }
    uint4 o;
    o.x = pack_bf(r[0], r[1]); o.y = pack_bf(r[2], r[3]);
    o.z = pack_bf(r[4], r[5]); o.w = pack_bf(r[6], r[7]);
    *reinterpret_cast<uint4*>(out + (size_t)node * C + cc) = o;
}

// GCN agg + self-loop + bias + split-store, fused final stage. bf16 yh, 16B
// gathers (4 threads/node x 8 channels); GCN edge weight from dis2 table.
__global__ void agg_gcn_final_kernel(const unsigned short* __restrict__ yh,
                                     const int* __restrict__ off,
                                     const unsigned int* __restrict__ ep,
                                     const float* __restrict__ dis2,
                                     const float* __restrict__ bmu,
                                     const float* __restrict__ bls,
                                     float* __restrict__ outp, int n) {
    int t = blockIdx.x * blockDim.x + threadIdx.x;
    if (t >= n * 4) return;
    int node = t >> 2;
    int cc = (t & 3) * 8;
    int beg = off[node], end = off[node + 1];
    float a0[8], a1[8];
    #pragma unroll
    for (int j = 0; j < 8; ++j) { a0[j] = 0.f; a1[j] = 0.f; }
    int e = beg;
    for (; e + 2 <= end; e += 2) {
        int s0 = rec_src(ep[e]), s1 = rec_src(ep[e + 1]);
        float w0 = dis2[s0], w1 = dis2[s1];
        uint4 q0 = *reinterpret_cast<const uint4*>(yh + (size_t)s0 * 32 + cc);
        uint4 q1 = *reinterpret_cast<const uint4*>(yh + (size_t)s1 * 32 + cc);
        float f[8];
        unpack_bf8(q0, f);
        #pragma unroll
        for (int j = 0; j < 8; ++j) a0[j] += w0 * f[j];
        unpack_bf8(q1, f);
        #pragma unroll
        for (int j = 0; j < 8; ++j) a1[j] += w1 * f[j];
    }
    for (; e < end; ++e) {
        int s = rec_src(ep[e]);
        float w = dis2[s];
        uint4 q = *reinterpret_cast<const uint4*>(yh + (size_t)s * 32 + cc);
        float f[8];
        unpack_bf8(q, f);
        #pragma unroll
        for (int j = 0; j < 8; ++j) a0[j] += w * f[j];
    }
    float d = dis2[node];
    uint4 qy = *reinterpret_cast<const uint4*>(yh + (size_t)node * 32 + cc);
    float yv[8];
    unpack_bf8(qy, yv);
    const float* bp = (cc < 16) ? (bmu + cc) : (bls + (cc - 16));
    float r[8];
    #pragma unroll
    for (int j = 0; j < 8; ++j)
        r[j] = d * (a0[j] + a1[j]) + d * d * yv[j] + bp[j];
    size_t o = (cc < 16) ? ((size_t)node * 16 + cc)
                         : ((size_t)n * 16 + (size_t)node * 16 + (cc - 16));
    *reinterpret_cast<float4*>(outp + o) = make_float4(r[0], r[1], r[2], r[3]);
    *reinterpret_cast<float4*>(outp + o + 4) = make_float4(r[4], r[5], r[6], r[7]);
}

// ----------------------------------------------------------------- matmul
__device__ __forceinline__ void fma4(float4& a, float s, const float4& w) {
    a.x += s * w.x; a.y += s * w.y; a.z += s * w.z; a.w += s * w.w;
}

// Fused multi-W matmul, bf16 weights staged in LDS.
// out_w[n0..n0+1, c0..c0+3] = X[n0..n0+1, :] @ W_w (+bias on w=0).
template <int KR, int PC, int NW, bool XBF, bool OBF, bool BIAS>
__global__ void mml_kernel(const void* __restrict__ Xv, const unsigned int* __restrict__ Wp,
                           const float* __restrict__ bp,
                           void* __restrict__ o0v, void* __restrict__ o1v,
                           void* __restrict__ o2v, void* __restrict__ o3v, int n) {
    constexpr int CP4 = PC / 4;
    constexpr int PCU = PC / 2;
    constexpr int WU = NW * KR * PCU;
    __shared__ __align__(16) unsigned int Wl[WU];
    __shared__ __align__(16) float bl[PC];
    {
        const uint4* s4 = reinterpret_cast<const uint4*>(Wp);
        uint4* d4 = reinterpret_cast<uint4*>(Wl);
        for (int i = threadIdx.x; i < WU / 4; i += blockDim.x) d4[i] = s4[i];
        if constexpr (BIAS)
            for (int i = threadIdx.x; i < PC; i += blockDim.x) bl[i] = bp[i];
    }
    __syncthreads();
    int idx = blockIdx.x * blockDim.x + threadIdx.x;
    if (idx >= (n >> 1) * CP4) return;
    int pair = idx / CP4;
    int c0 = (idx - pair * CP4) * 4;
    int n0 = pair * 2;
    const float* xaf = (const float*)Xv + (size_t)n0 * KR;
    const float* xbf = xaf + KR;
    const unsigned short* xah = (const unsigned short*)Xv + (size_t)n0 * KR;
    const unsigned short* xbh = xah + KR;
    const unsigned int* wc = Wl + (c0 >> 1);
    float4 acc[2][NW];
    #pragma unroll
    for (int w = 0; w < NW; ++w) {
        acc[0][w] = make_float4(0.f, 0.f, 0.f, 0.f);
        acc[1][w] = acc[0][w];
    }
    if constexpr (BIAS) {
        acc[0][0] = *reinterpret_cast<const float4*>(&bl[c0]);
        acc[1][0] = acc[0][0];
    }
    #pragma unroll 2
    for (int k4 = 0; k4 < KR / 4; ++k4) {
        float4 va, vb;
        if constexpr (XBF) {
            va = unpack_bf4(*reinterpret_cast<const uint2*>(xah + k4 * 4));
            vb = unpack_bf4(*reinterpret_cast<const uint2*>(xbh + k4 * 4));
        } else {
            va = *reinterpret_cast<const float4*>(xaf + k4 * 4);
            vb = *reinterpret_cast<const float4*>(xbf + k4 * 4);
        }
        #pragma unroll
        for (int j = 0; j < 4; ++j) {
            int k = k4 * 4 + j;
            float sa = (&va.x)[j];
            float sb = (&vb.x)[j];
            #pragma unroll
            for (int w = 0; w < NW; ++w) {
                uint2 q = *reinterpret_cast<const uint2*>(wc + (size_t)(w * KR + k) * PCU);
                float4 wv = unpack_bf4(q);
                fma4(acc[0][w], sa, wv);
                fma4(acc[1][w], sb, wv);
            }
        }
    }
    void* outs[4] = {o0v, o1v, o2v, o3v};
    #pragma unroll
    for (int w = 0; w < NW; ++w) {
        if constexpr (OBF) {
            unsigned short* o = (unsigned short*)outs[w] + (size_t)n0 * PC + c0;
            *reinterpret_cast<uint2*>(o) =
                make_uint2(pack_bf(acc[0][w].x, acc[0][w].y), pack_bf(acc[0][w].z, acc[0][w].w));
            *reinterpret_cast<uint2*>(o + PC) =
                make_uint2(pack_bf(acc[1][w].x, acc[1][w].y), pack_bf(acc[1][w].z, acc[1][w].w));
        } else {
            float* o = (float*)outs[w] + (size_t)n0 * PC + c0;
            *reinterpret_cast<float4*>(o) = acc[0][w];
            *reinterpret_cast<float4*>(o + PC) = acc[1][w];
        }
    }
}

// ------------------------------------------------------------------ launch

extern "C" void kernel_launch(void* const* d_in, const int* in_sizes, int n_in,
                              void* d_out, int out_size, void* d_ws, size_t ws_size,
                              hipStream_t stream) {
    const float* x   = (const float*)d_in[0];
    const int*   ei  = (const int*)d_in[1];
    const float* W1  = (const float*)d_in[2];
    const float* b1  = (const float*)d_in[3];
    const float* W2  = (const float*)d_in[4];
    const float* b2  = (const float*)d_in[5];
    const float* Wmu = (const float*)d_in[6];
    const float* bmu = (const float*)d_in[7];
    const float* Wls = (const float*)d_in[8];
    const float* bls = (const float*)d_in[9];
    float* out = (float*)d_out;

    const int N = NN, E = EE;
    const int* row = ei;
    const int* col = ei + E;

    // workspace carve-up (256B aligned)
    char* p = (char*)d_ws;
    auto alloc = [&](size_t bytes) -> char* {
        char* r = p;
        p += (bytes + 255) & ~(size_t)255;
        return r;
    };
    int*   deg    = (int*)alloc((size_t)N * 4);
    int*   off    = (int*)alloc((size_t)(N + 1) * 4);
    int*   bsum   = (int*)alloc((size_t)256 * 4);
    float* dis    = (float*)alloc((size_t)N * 4);
    float* dis2   = (float*)alloc((size_t)N * 4);
    unsigned int* wB = (unsigned int*)alloc((size_t)TUW * 4);
    float* bB     = (float*)alloc((size_t)NBF * 4);
    unsigned int* eTag = (unsigned int*)alloc((size_t)E * 4);
    unsigned int* rr   = (unsigned int*)alloc((size_t)E * 4);
    unsigned short* y0 = (unsigned short*)alloc((size_t)N * S1 * 2);
    unsigned short* y1 = (unsigned short*)alloc((size_t)N * S1 * 2);
    unsigned short* y2 = (unsigned short*)alloc((size_t)N * S1 * 2);
    unsigned short* y3 = (unsigned short*)alloc((size_t)N * S1 * 2);
    unsigned short* u0 = (unsigned short*)alloc((size_t)N * S2P * 2);
    unsigned short* u1 = (unsigned short*)alloc((size_t)N * S2P * 2);
    unsigned short* u2 = (unsigned short*)alloc((size_t)N * S2P * 2);
    unsigned short* u3 = (unsigned short*)alloc((size_t)N * S2P * 2);
    unsigned short* yh = (unsigned short*)alloc((size_t)N * 32 * 2);

    const unsigned int* W1b = wB;
    const unsigned int* W2b = wB + NU1;
    const unsigned int* Whb = wB + NU1 + NU2;
    const float* b1p = bB;
    const float* b2p = bB + S1;

    const int B = 256;
    int gE = (E + B - 1) / B;
    int nb = (N + SB - 1) / SB;  // 196 scan blocks

    // --- graph preprocessing -> CSR by destination (+ weight repack to bf16)
    init_kernel<<<nb, B, 0, stream>>>(W1, b1, W2, b2, Wmu, Wls, wB, bB, deg);
    hist_kernel<<<gE, B, 0, stream>>>(row, col, deg, rr, E);
    reduce_kernel<<<nb, SB, 0, stream>>>(deg, bsum, N);
    block_scan_kernel<<<nb, SB, 0, stream>>>(deg, bsum, off, dis, dis2, N, nb);
    fill_kernel<<<3200, B, 0, stream>>>(col, rr, dis, off, eTag, E);

    // grids
    int gm1 = ((N / 2) * (S1 / 4) + B - 1) / B;   // 1758
    int gm2 = ((N / 2) * (S2P / 4) + B - 1) / B;  // 1172
    int gmh = ((N / 2) * 8 + B - 1) / B;          // 782
    int ga72 = (N * (S1 / 8) + B - 1) / B;        // TPN 9
    int ga48 = (N * (S2P / 8) + B - 1) / B;       // TPN 6
    int gaF  = (N * 4 + B - 1) / B;               // TPN 4

    // --- TAG layer 1 via Horner: o1 = relu(y0 + A(y1 + A(y2 + A*y3)))
    mml_kernel<CIN, S1, 2, false, true, true ><<<gm1, B, 0, stream>>>(
        x, W1b, b1p, y0, y1, nullptr, nullptr, N);
    mml_kernel<CIN, S1, 2, false, true, false><<<gm1, B, 0, stream>>>(
        x, W1b + 2 * IMG1U, nullptr, y2, y3, nullptr, nullptr, N);
    aggw_kernel<S1, true, false><<<ga72, B, 0, stream>>>(y3, y2, y2, off, eTag, N);
    aggw_kernel<S1, true, false><<<ga72, B, 0, stream>>>(y2, y1, y1, off, eTag, N);
    aggw_kernel<S1, true, true ><<<ga72, B, 0, stream>>>(y1, y0, y0, off, eTag, N);
    // o1 = y0 (bf16, stride S1, pad cols zero)

    // --- TAG layer 2 via Horner: o2 = relu(u0 + A(u1 + A(u2 + A*u3)))
    mml_kernel<S1, S2P, 4, true, true, true ><<<gm2, B, 0, stream>>>(
        y0, W2b, b2p, u0, u1, u2, u3, N);
    aggw_kernel<S2P, true, false><<<ga48, B, 0, stream>>>(u3, u2, u2, off, eTag, N);
    aggw_kernel<S2P, true, false><<<ga48, B, 0, stream>>>(u2, u1, u1, off, eTag, N);
    aggw_kernel<S2P, true, true ><<<ga48, B, 0, stream>>>(u1, u0, u0, off, eTag, N);
    // o2 = u0 (bf16, stride S2P, pad cols zero)

    // --- GCN heads: head matmul (bf16 in LDS, bf16 out), then fused final agg
    mml_kernel<S2P, 32, 1, true, true, false><<<gmh, B, 0, stream>>>(
        u0, Whb, nullptr, yh, nullptr, nullptr, nullptr, N);
    agg_gcn_final_kernel<<<gaF, B, 0, stream>>>(yh, off, eTag, dis2, bmu, bls, out, N);
}